// Round 2
// baseline (540.534 us; speedup 1.0000x reference)
//
#include <hip/hip_runtime.h>
#include <math.h>

// Problem constants (setup_inputs: block_size=2048, embedding_dim=256)
#define PB 2048
#define PD 256
// K = D/2 - 1 = 127 loop iterations in the reference.
//
// Single fused pass: write every 16B quad of the 512 MiB output exactly once
// (zeros + the ~782k nonzeros). Minimum HBM traffic: pure 512 MiB write, no
// fetch. Round-0 variant of this ran at 3.25 TB/s with nontemporal stores;
// theory: nt bypasses L2 write-combining -> isolated 16B writes at the MC.
// This version uses plain stores + grid-stride loop like the runtime fill
// kernel (measured 6.3 TB/s on this same buffer).

typedef float f32x4 __attribute__((ext_vector_type(4)));

// theta_i = 10000^(-2*(i-1)/D)  [the (i-1) quirk is intentional, per reference]
//         = exp2( -(i-1) * 2*log2(10000)/256 )
__device__ __forceinline__ float theta_of(int i) {
    const float c = 0.10381025187f; // 2*log2(10000)/256
    return exp2f(-(float)(i - 1) * c);
}

// Flat quad index q:
//   col = (q & 63) * 4 ; row r = (q >> 6) & 255 ; plane p = q >> 14
// A wave's 64 contiguous quads cover exactly one row -> row logic is
// wave-uniform; only ~2 lanes of even-row waves do trig.
// Nonzero entries of row r (r even, j = r/2):
//   col r-2 :  sin(p * theta_{j-1})   (j >= 1)
//   col r   :  cos(p * theta_{min(j,126)})
//   col r+2 : -sin(p * theta_j)       (j <= 126)
// All special cols are even -> only quad components 0 and 2 can be nonzero.
__global__ __launch_bounds__(256) void rope_fill_kernel(float* __restrict__ out) {
    f32x4* o = reinterpret_cast<f32x4*>(out);
    const unsigned int total  = (unsigned int)PB * PD * (PD / 4); // 33,554,432 quads
    const unsigned int stride = gridDim.x * blockDim.x;           // 1,048,576
    for (unsigned int q = blockIdx.x * blockDim.x + threadIdx.x; q < total; q += stride) {
        f32x4 v = {0.0f, 0.0f, 0.0f, 0.0f};
        int col = (int)(q & 63u) * 4;
        int r   = (int)((q >> 6) & 255u);
        if ((r & 1) == 0) {
            int d = r - col; // candidates overlap this quad iff d in {-2,0,2,4}
            if (d >= -2 && d <= 4) {
                int p = (int)(q >> 14);
                float fp = (float)p;
                int j = r >> 1;
                if (d == -2) {
                    // comp0 = col = r+2
                    if (j <= 126) v.x = -sinf(fp * theta_of(j));
                } else if (d == 0) {
                    // comp0 = r (diag), comp2 = r+2
                    v.x = cosf(fp * theta_of(j < 126 ? j : 126));
                    if (j <= 126) v.z = -sinf(fp * theta_of(j));
                } else if (d == 2) {
                    // comp0 = r-2, comp2 = r (diag)
                    if (j >= 1) v.x = sinf(fp * theta_of(j - 1));
                    v.z = cosf(fp * theta_of(j < 126 ? j : 126));
                } else { // d == 4
                    // comp2 = col+2 = r-2
                    if (j >= 1) v.z = sinf(fp * theta_of(j - 1));
                }
            }
        }
        o[q] = v; // plain store: let L2 write-combine full lines
    }
}

extern "C" void kernel_launch(void* const* d_in, const int* in_sizes, int n_in,
                              void* d_out, int out_size, void* d_ws, size_t ws_size,
                              hipStream_t stream) {
    (void)d_in; (void)in_sizes; (void)n_in; (void)d_ws; (void)ws_size;
    const int threads = 256;
    const int blocks  = 4096; // 1M threads, 32 quads each; 16 blocks/CU
    rope_fill_kernel<<<blocks, threads, 0, stream>>>((float*)d_out);
}

// Round 3
// 538.117 us; speedup vs baseline: 1.0045x; 1.0045x over previous
//
#include <hip/hip_runtime.h>
#include <math.h>

// Problem constants (setup_inputs: block_size=2048, embedding_dim=256)
#define PB 2048
#define PD 256
// K = D/2 - 1 = 127 reference iterations. Nonzero pattern of plane p:
//   row 2i:   col 2i -> cos(p*th_i), col 2i+2 -> -sin(p*th_i)
//   row 2i+2: col 2i -> sin(p*th_i); final diag (254,254) -> cos(p*th_126)
//
// Design (post-mortem of rounds 0-2): fused one-pass fill is minimum-traffic
// (512 MiB pure write), but libm trig *inside* the fill path serializes
// divergent branches per even-row wave (~6 lane-sparse sinf/cosf calls) and
// was the real limiter (165-190 us vs 85 us store floor). So: precompute all
// sin/cos into a 2 MiB workspace table (kernel 1), then the fill kernel does
// 3 wave-uniform L2-hit loads + branch-free cndmasks per even row.

typedef float f32x4 __attribute__((ext_vector_type(4)));

// theta_i = 10000^(-2*(i-1)/D)  [the (i-1) quirk is intentional, per reference]
//         = exp2( -(i-1) * 2*log2(10000)/256 )
__device__ __forceinline__ float theta_of(int i) {
    const float c = 0.10381025187f; // 2*log2(10000)/256
    return exp2f(-(float)(i - 1) * c);
}

#define TABLE_FLOATS (PB * 128 * 2)              // [p][i][{sin,cos}]
#define TABLE_BYTES  (TABLE_FLOATS * sizeof(float))

// Kernel 1: tab[(p*128+i)*2+0] = sin(p*theta_i), +1 = cos(p*theta_i).
// 2048*128 = 262,144 threads, one sincos each. Same math as prior rounds.
__global__ __launch_bounds__(256) void rope_table_kernel(float* __restrict__ tab) {
    unsigned int tid = blockIdx.x * blockDim.x + threadIdx.x; // < 2^18
    int i = (int)(tid & 127u);
    int p = (int)(tid >> 7);
    float m = (float)p * theta_of(i);
    float s, c;
    __builtin_sincosf(m, &s, &c);
    tab[tid * 2u + 0u] = s;
    tab[tid * 2u + 1u] = c;
}

// Kernel 2: one wave per output row (64 lanes x 16B = 1024B = one row).
// Even-row waves fetch {sin_{j-1}, sin_j, cos_{min(j,126)}} (wave-uniform,
// L2-resident) and predicate them into quad components; odd rows store zeros.
__global__ __launch_bounds__(256) void rope_fill_kernel(float* __restrict__ out,
                                                        const float* __restrict__ tab) {
    f32x4* o = reinterpret_cast<f32x4*>(out);
    const unsigned int nrows = (unsigned int)PB * PD;        // 524,288
    const unsigned int nw    = (gridDim.x * blockDim.x) >> 6;
    unsigned int gw   = (blockIdx.x * blockDim.x + threadIdx.x) >> 6;
    int lane = (int)(threadIdx.x & 63u);
    int col0 = lane * 4;

    for (unsigned int R = gw; R < nrows; R += nw) {
        int r = (int)(R & 255u);
        f32x4 v = {0.0f, 0.0f, 0.0f, 0.0f};
        if ((r & 1) == 0) {
            int p = (int)(R >> 8);
            int j = r >> 1;                          // 0..127
            const float* tp = tab + (unsigned int)p * 256u; // p*128*2
            float ssub = tp[(unsigned int)(j >= 1 ? j - 1 : 0) * 2u + 0u]; // sin(p*th_{j-1})
            float ssup = tp[(unsigned int)j * 2u + 0u];                    // sin(p*th_j)
            float c    = tp[(unsigned int)(j < 126 ? j : 126) * 2u + 1u];  // cos
            int d = r - col0;
            // comp0 is col col0; comp2 is col col0+2. (j-range guards are
            // implied by column existence: d==2 requires r>=2 -> j>=1, etc.)
            v.x = (d == 2) ? ssub : (d == 0) ? c : (d == -2) ? -ssup : 0.0f;
            v.z = (d == 4) ? ssub : (d == 2) ? c : (d == 0) ? -ssup : 0.0f;
        }
        o[R * 64u + (unsigned int)lane] = v;
    }
}

// Fallback fixup (round-1 structure) if workspace is too small for the table.
__global__ __launch_bounds__(256) void rope_fixup_kernel(float* __restrict__ out) {
    unsigned int tid = blockIdx.x * blockDim.x + threadIdx.x;
    int i = (int)(tid & 127u);
    int p = (int)(tid >> 7);
    float fp = (float)p;
    unsigned int base = (unsigned int)p * (unsigned int)(PD * PD);
    if (i < 127) {
        float m = fp * theta_of(i);
        float s, c;
        __builtin_sincosf(m, &s, &c);
        unsigned int r = 2u * (unsigned int)i;
        out[base + r * PD + r]        = c;
        out[base + r * PD + r + 2u]   = -s;
        out[base + (r + 2u) * PD + r] = s;
    } else {
        out[base + 254u * PD + 254u] = cosf(fp * theta_of(126));
    }
}

extern "C" void kernel_launch(void* const* d_in, const int* in_sizes, int n_in,
                              void* d_out, int out_size, void* d_ws, size_t ws_size,
                              hipStream_t stream) {
    (void)d_in; (void)in_sizes; (void)n_in;
    if (ws_size >= (size_t)TABLE_BYTES) {
        float* tab = (float*)d_ws;
        rope_table_kernel<<<PB * 128 / 256, 256, 0, stream>>>(tab);
        // 4096 blocks x 4 waves = 16384 waves, 32 rows each; 16 blocks/CU.
        rope_fill_kernel<<<4096, 256, 0, stream>>>((float*)d_out, tab);
    } else {
        hipMemsetAsync(d_out, 0, (size_t)out_size, stream);
        rope_fixup_kernel<<<PB * 128 / 256, 256, 0, stream>>>((float*)d_out);
    }
}

// Round 4
// 469.976 us; speedup vs baseline: 1.1501x; 1.1450x over previous
//
#include <hip/hip_runtime.h>
#include <math.h>

// Problem constants (setup_inputs: block_size=2048, embedding_dim=256)
#define PB 2048
#define PD 256
// K = D/2 - 1 = 127 reference iterations. Nonzero pattern of plane p:
//   row 2i (i=0..126): col 2i -> cos(p*th_i), col 2i+2 -> -sin(p*th_i)
//   row 2i+2:          col 2i -> sin(p*th_i)
//   final diag (254,254) -> cos(p*th_126); odd rows/cols all zero.
//
// Ledger (rounds 0-3): custom fused fill kernels cap at ~2.9-3.3 TB/s of
// stores (~2x the rocclr fillBufferAligned's 6.3 TB/s on this same buffer),
// invariant to trig/divergence/store-flavor/grid. So: zero via the runtime
// fill path (hipMemsetAsync), then a band-fixup that writes FULL 256B
// aligned line-windows (one wave per even row, 64 lanes x 4B coalesced) --
// no partial-sector RMW, ~64 MiB pure writes.

// theta_i = 10000^(-2*(i-1)/D)  [the (i-1) quirk is intentional, per reference]
//         = exp2( -(i-1) * 2*log2(10000)/256 )
__device__ __forceinline__ float theta_of(int i) {
    const float c = 0.10381025187f; // 2*log2(10000)/256
    return exp2f(-(float)(i - 1) * c);
}

#define TABLE_FLOATS (PB * 128 * 2)              // [p][i][{sin,cos}]
#define TABLE_BYTES  (TABLE_FLOATS * sizeof(float))

// Kernel 1: tab[(p*128+i)*2+0] = sin(p*theta_i), +1 = cos(p*theta_i).
// Lane-parallel sincos: 4096 waves, one sincos per lane. ~4 us.
__global__ __launch_bounds__(256) void rope_table_kernel(float* __restrict__ tab) {
    unsigned int tid = blockIdx.x * blockDim.x + threadIdx.x; // < 2^18
    int i = (int)(tid & 127u);
    int p = (int)(tid >> 7);
    float m = (float)p * theta_of(i);
    float s, c;
    __builtin_sincosf(m, &s, &c);
    tab[tid * 2u + 0u] = s;
    tab[tid * 2u + 1u] = c;
}

// Kernel 2 (after memset): one wave per (plane p, even row r). The wave
// writes one 256B-aligned 64-float window covering cols {r-2, r, r+2};
// all other cols in the window are zero (correct: row r's only nonzeros
// are those three). Full-line coalesced stores -> no read-modify-write.
__global__ __launch_bounds__(256) void rope_band_kernel(float* __restrict__ out,
                                                        const float* __restrict__ tab) {
    unsigned int W = (blockIdx.x * blockDim.x + threadIdx.x) >> 6; // wave id < 262144
    int lane = (int)(threadIdx.x & 63u);
    int p = (int)(W >> 7);          // 0..2047
    int r = (int)(W & 127u) * 2;    // even row 0..254
    int j = r >> 1;                 // 0..127

    const float* tp = tab + (unsigned int)p * 256u; // p*128*2
    float ssub = tp[(unsigned int)(j >= 1 ? j - 1 : 0) * 2u + 0u]; // sin(p*th_{j-1})
    float ssup = tp[(unsigned int)j * 2u + 0u];                    // sin(p*th_j)
    float c    = tp[(unsigned int)(j < 126 ? j : 126) * 2u + 1u];  // cos(p*th_min(j,126))

    // 64-col window, 128B-aligned, containing cols r-2..r+2; base <= 192 so
    // the window stays inside the 256-col row.
    int base = (r >= 2) ? ((r - 2) & ~31) : 0;
    if (base > 192) base = 192;
    int col = base + lane;

    // Guards are implicit: col==r-2 unreachable when r==0; col==r+2
    // unreachable when r==254 (col max 255). Unselected table reads are
    // clamped in-bounds above.
    float val = (col == r) ? c
              : (col == r - 2) ? ssub
              : (col == r + 2) ? -ssup
              : 0.0f;

    out[(unsigned int)p * 65536u + (unsigned int)r * 256u + (unsigned int)col] = val;
}

// Fallback (round-1 structure) if workspace can't hold the table.
__global__ __launch_bounds__(256) void rope_fixup_kernel(float* __restrict__ out) {
    unsigned int tid = blockIdx.x * blockDim.x + threadIdx.x;
    int i = (int)(tid & 127u);
    int p = (int)(tid >> 7);
    float fp = (float)p;
    unsigned int base = (unsigned int)p * (unsigned int)(PD * PD);
    if (i < 127) {
        float m = fp * theta_of(i);
        float s, c;
        __builtin_sincosf(m, &s, &c);
        unsigned int r = 2u * (unsigned int)i;
        out[base + r * PD + r]        = c;
        out[base + r * PD + r + 2u]   = -s;
        out[base + (r + 2u) * PD + r] = s;
    } else {
        out[base + 254u * PD + 254u] = cosf(fp * theta_of(126));
    }
}

extern "C" void kernel_launch(void* const* d_in, const int* in_sizes, int n_in,
                              void* d_out, int out_size, void* d_ws, size_t ws_size,
                              hipStream_t stream) {
    (void)d_in; (void)in_sizes; (void)n_in;
    if (ws_size >= (size_t)TABLE_BYTES) {
        float* tab = (float*)d_ws;
        // table (writes d_ws) -> memset (runtime 6.3 TB/s fill path) -> band
        rope_table_kernel<<<PB * 128 / 256, 256, 0, stream>>>(tab);
        hipMemsetAsync(d_out, 0, (size_t)out_size, stream);
        // 262144 waves = 16,777,216 threads; one 256B window each.
        rope_band_kernel<<<65536, 256, 0, stream>>>((float*)d_out, tab);
    } else {
        hipMemsetAsync(d_out, 0, (size_t)out_size, stream);
        rope_fixup_kernel<<<PB * 128 / 256, 256, 0, stream>>>((float*)d_out);
    }
}

// Round 5
// 452.952 us; speedup vs baseline: 1.1934x; 1.0376x over previous
//
#include <hip/hip_runtime.h>
#include <math.h>

// Problem constants (setup_inputs: block_size=2048, embedding_dim=256)
#define PB 2048
#define PD 256
// K = D/2 - 1 = 127 reference iterations. Nonzero pattern of plane p:
//   row 2i (i=0..126): col 2i -> cos(p*th_i), col 2i+2 -> -sin(p*th_i)
//   row 2i+2:          col 2i -> sin(p*th_i)
//   final diag (254,254) -> cos(p*th_126); odd rows/cols all zero.
//
// Session ledger:
//   fused one-pass custom fill: ~2.9-3.3 TB/s stores regardless of trig/
//     divergence/store-flavor/grid (R0/R2/R3) -> abandoned.
//   hipMemsetAsync (runtime fill path, measured 6.3 TB/s on these pages)
//     + sparse fixup: ~125 us our-portion (R1/R4) -> keep, minimize overhead.
// This round: delete the table kernel + one launch. The band kernel computes
// its own sincos lane-parallel (no divergence, no table traffic): one block
// per plane, each wave owns 32 even rows, lanes compute exactly the 33
// sin/cos values those rows need, broadcast by compile-time-lane __shfl.

// theta_i = 10000^(-2*(i-1)/D)  [the (i-1) quirk is intentional, per reference]
//         = exp2( -(i-1) * 2*log2(10000)/256 )
__device__ __forceinline__ float theta_of(int i) {
    const float c = 0.10381025187f; // 2*log2(10000)/256
    return exp2f(-(float)(i - 1) * c);
}

// One block per plane p; wave w (of 4) handles even rows r=2j, j in
// [32w, 32w+32). Lane l computes sincos(p * th_{clamp(32w-1+l)}) so that
// within the wave, lane t   holds th_{j-1} for j = 32w+t   (ssub),
//                  lane t+1 holds th_j                      (ssup, cos).
// Each row stores one 256B-aligned 64-float window covering cols
// {r-2, r, r+2} (full-line coalesced, no RMW); memset provides the rest.
__global__ __launch_bounds__(256) void rope_band2_kernel(float* __restrict__ out) {
    int p    = (int)blockIdx.x;          // 0..2047
    int w    = (int)(threadIdx.x >> 6);  // 0..3
    int lane = (int)(threadIdx.x & 63u);

    int i = 32 * w - 1 + lane;           // value index this lane computes
    i = (i < 0) ? 0 : (i > 127 ? 127 : i);
    float s, c;
    __builtin_sincosf((float)p * theta_of(i), &s, &c);

    float* plane = out + (unsigned int)p * 65536u;

    #pragma unroll
    for (int t = 0; t < 32; ++t) {
        int j = 32 * w + t;              // 0..127
        int r = 2 * j;                   // even row 0..254
        // broadcasts: lane indices are compile-time constants (unrolled)
        float ssub = __shfl(s, t, 64);        // sin(p*th_{j-1}) (j>=1)
        float ssup = __shfl(s, t + 1, 64);    // sin(p*th_j)
        float cj   = __shfl(c, t + 1, 64);    // cos(p*th_j)
        float cjm1 = __shfl(c, t, 64);        // cos(p*th_{j-1})
        float cv   = (j == 127) ? cjm1 : cj;  // cos(p*th_min(j,126)); uniform sel

        // 64-col window, 128B-aligned, containing cols r-2..r+2, inside row.
        int base = (r >= 2) ? ((r - 2) & ~31) : 0;
        if (base > 192) base = 192;
        int col = base + lane;

        // col==r-2 unreachable for r==0 (would be -2); col==r+2 unreachable
        // for r==254 (max col 255): guards are implicit.
        float val = (col == r) ? cv
                  : (col == r - 2) ? ssub
                  : (col == r + 2) ? -ssup
                  : 0.0f;

        plane[(unsigned int)r * 256u + (unsigned int)col] = val;
    }
}

extern "C" void kernel_launch(void* const* d_in, const int* in_sizes, int n_in,
                              void* d_out, int out_size, void* d_ws, size_t ws_size,
                              hipStream_t stream) {
    (void)d_in; (void)in_sizes; (void)n_in; (void)d_ws; (void)ws_size;
    // 1) Zero the 512 MiB output on the runtime fill path (~6.3 TB/s).
    hipMemsetAsync(d_out, 0, (size_t)out_size, stream);
    // 2) Scatter the band: 2048 blocks (one per plane) x 256 threads;
    //    8 blocks/CU, 64 MiB of full-line coalesced stores.
    rope_band2_kernel<<<PB, 256, 0, stream>>>((float*)d_out);
}